// Round 11
// baseline (293.014 us; speedup 1.0000x reference)
//
#include <hip/hip_runtime.h>
#include <hip/hip_bf16.h>

#define N_NODES 50000
#define N_EDGES 1600000
#define NGRAPH  16
#define HID     128

#define RPB   128                           // rows per bucket
#define NB    ((N_NODES + RPB - 1) / RPB)   // 391 buckets
#define NBLK  256                           // partition blocks
#define EPB   ((N_EDGES + NBLK - 1) / NBLK) // 6250 edges per partition block
#define P4CAP 6144                          // LDS cache entries for a bucket run (mean 4092, sd 64)

typedef unsigned int uint32;
typedef unsigned short ushort;
typedef unsigned char uchar;
typedef __attribute__((ext_vector_type(8))) short bf16x8;
typedef __attribute__((ext_vector_type(4))) float f32x4;
typedef __attribute__((ext_vector_type(2))) float f32x2;

// bf16 round-to-nearest-even helpers
__device__ __forceinline__ uint32 bf16r(float f) {
    uint32 b = __float_as_uint(f);
    return (b + 0x7fffu + ((b >> 16) & 1u)) >> 16;
}
__device__ __forceinline__ uint32 pack_bf16(float lo, float hi) {
    return bf16r(lo) | (bf16r(hi) << 16);
}

// ---------------- P1 + init (fused): per-(bucket,block) histogram; block-parallel
//                  weight prep (W2/W7 B-frag pack, v3) and pooled zeroing ----------------
__global__ __launch_bounds__(1024) void k_p1i(const int* __restrict__ row,
                                              int* __restrict__ blkhist,
                                              float* __restrict__ zp, int nz,
                                              const float* __restrict__ W2,
                                              const float* __restrict__ W7,
                                              const float* __restrict__ W3,
                                              const float* __restrict__ W4,
                                              ushort* __restrict__ wpack,
                                              float* __restrict__ v3) {
    __shared__ int hist[NB];
    int tid = threadIdx.x, blk = blockIdx.x;
    int gid = blk * 1024 + tid;
    // --- init work (independent of hist) ---
    if (gid < nz) zp[gid] = 0.f;
    if (gid < 4 * 16384) {
        int m = gid >> 14, f = gid & 16383;
        int j = f & 7, lane = (f >> 3) & 63, kk = (f >> 9) & 3, t = (f >> 11) & 7;
        int hp = t * 16 + (lane & 15);
        int k  = kk * 32 + ((lane >> 4) & 3) * 8 + j;
        const float* src = (m < 3) ? (W2 + m * HID * HID) : W7;
        wpack[gid] = (ushort)bf16r(src[hp * HID + k]);
    }
    if (gid < 3 * HID) {
        int l = gid / HID, hp = gid % HID;
        float acc = 0.f;
        for (int h = 0; h < HID; h++)
            acc += W3[l * HID * HID + hp * HID + h] * fmaxf(W4[l * HID + h], 0.f);
        v3[gid] = acc;
    }
    // --- histogram ---
    for (int i = tid; i < NB; i += 1024) hist[i] = 0;
    __syncthreads();
    int s = blk * EPB, e = s + EPB; if (e > N_EDGES) e = N_EDGES;
    for (int i = s + tid; i < e; i += 1024)
        atomicAdd(&hist[row[i] >> 7], 1);
    __syncthreads();
    for (int i = tid; i < NB; i += 1024)
        blkhist[i * NBLK + blk] = hist[i];
}

// ------- P2a: per-bucket exclusive scan over its NBLK per-block counts -------
__global__ __launch_bounds__(NBLK) void k_p2a(int* __restrict__ blkhist,
                                              int* __restrict__ btot) {
    __shared__ int sums[NBLK];
    int t = threadIdx.x, b = blockIdx.x;
    int v = blkhist[b * NBLK + t];
    sums[t] = v;
    __syncthreads();
    for (int d = 1; d < NBLK; d <<= 1) {
        int u = (t >= d) ? sums[t - d] : 0;
        __syncthreads();
        sums[t] += u;
        __syncthreads();
    }
    blkhist[b * NBLK + t] = sums[t] - v;     // local exclusive
    if (t == NBLK - 1) btot[b] = sums[t];    // bucket total
}

// ------- P3: scatter int2{rowlocal:8|col:16, ea} into bucket runs -------
// (bucket bases recomputed per-block from btot via LDS scan)
__global__ __launch_bounds__(1024) void k_p3_part(const int* __restrict__ row,
                                                  const int* __restrict__ col,
                                                  const float* __restrict__ ea,
                                                  const int* __restrict__ blkhist,
                                                  const int* __restrict__ btot,
                                                  int2* __restrict__ pea) {
    __shared__ int sc[512];
    __shared__ int cur[NB];
    int tid = threadIdx.x, blk = blockIdx.x;
    if (tid < 512) sc[tid] = (tid < NB) ? btot[tid] : 0;
    __syncthreads();
    for (int d = 1; d < 512; d <<= 1) {
        int v = 0;
        if (tid < 512 && tid >= d) v = sc[tid - d];
        __syncthreads();
        if (tid < 512) sc[tid] += v;
        __syncthreads();
    }
    for (int i = tid; i < NB; i += 1024)
        cur[i] = (sc[i] - btot[i]) + blkhist[i * NBLK + blk];
    __syncthreads();
    int s = blk * EPB, e = s + EPB; if (e > N_EDGES) e = N_EDGES;
    for (int i = s + tid; i < e; i += 1024) {
        int r = row[i], c = col[i];
        float a = ea[i];
        int slot = atomicAdd(&cur[r >> 7], 1);
        pea[slot] = make_int2(((r & (RPB - 1)) << 16) | c, __float_as_int(a));
    }
}

// ------- P4: bucket run staged in LDS once; counts+scan -> offs/ea_sum, scatter csr,
//         and materialize emb0 = relu(x*w1 + ea_sum*v3) as PLANAR fp8 half-rows
//         (Lo: dims 0-63, Hi: dims 64-127; 3.2 MB each -> per-XCD L2 resident). -------
__global__ __launch_bounds__(512) void k_p4(const int2* __restrict__ pea,
                                            const int* __restrict__ btot,
                                            const float* __restrict__ x,
                                            int* __restrict__ offs,
                                            float* __restrict__ ea_sum,
                                            int* __restrict__ csr,
                                            uchar* __restrict__ emb0Lo,
                                            uchar* __restrict__ emb0Hi,
                                            const float* __restrict__ w1l0,
                                            const float* __restrict__ v3l0) {
    __shared__ int2  cache[P4CAP];   // 48 KB
    __shared__ int   red[512];
    __shared__ int   cnt[RPB];
    __shared__ float eas[RPB];
    __shared__ int   scan_s[RPB];
    __shared__ int   curp[RPB];
    int t = threadIdx.x, b = blockIdx.x;
    // bucket base s = sum(btot[0..b)), e = s + btot[b]
    red[t] = (t < b) ? btot[t] : 0;          // t<b implies t<NB
    __syncthreads();
    for (int d = 256; d > 0; d >>= 1) {
        if (t < d) red[t] += red[t + d];
        __syncthreads();
    }
    int s = red[0];
    int e = s + btot[b];
    int len = e - s;
    int clen = len < P4CAP ? len : P4CAP;    // statistical bound: len never exceeds P4CAP
    for (int i = t; i < clen; i += 512) cache[i] = pea[s + i];
    if (t < RPB) { cnt[t] = 0; eas[t] = 0.f; }
    __syncthreads();
    // pass 1: per-node counts + ea sums
    for (int i = t; i < len; i += 512) {
        int2 p = (i < P4CAP) ? cache[i] : pea[s + i];
        int lr = ((uint32)p.x) >> 16;
        atomicAdd(&cnt[lr], 1);
        atomicAdd(&eas[lr], __int_as_float(p.y));
    }
    __syncthreads();
    if (t < RPB) scan_s[t] = cnt[t];
    __syncthreads();
    for (int d = 1; d < RPB; d <<= 1) {
        int v = 0;
        if (t < RPB && t >= d) v = scan_s[t - d];
        __syncthreads();
        if (t < RPB) scan_s[t] += v;
        __syncthreads();
    }
    int nbase = b * RPB;
    if (t < RPB) {
        int excl = scan_s[t] - cnt[t];
        int n = nbase + t;
        if (n < N_NODES) {
            offs[n] = s + excl;
            ea_sum[n] = eas[t];
        }
        curp[t] = s + excl;
    }
    if (b == NB - 1 && t == 0) offs[N_NODES] = e;
    __syncthreads();
    // pass 2: scatter csr from the LDS-cached run
    for (int i = t; i < len; i += 512) {
        int2 p = (i < P4CAP) ? cache[i] : pea[s + i];
        int slot = atomicAdd(&curp[((uint32)p.x) >> 16], 1);
        csr[slot] = p.x & 0xFFFF;
    }
    // epilogue: emb0 planar fp8 half-rows for this bucket's 128 nodes
    for (int i = t; i < RPB * 32; i += 512) {
        int lr = i >> 5, c4 = (i & 31) * 4;
        int n = nbase + lr;
        if (n < N_NODES) {
            float xv = x[n];
            float ev = eas[lr];
            float v0 = fmaxf(xv * w1l0[c4 + 0] + ev * v3l0[c4 + 0], 0.f) * 0.015625f;
            float v1 = fmaxf(xv * w1l0[c4 + 1] + ev * v3l0[c4 + 1], 0.f) * 0.015625f;
            float v2 = fmaxf(xv * w1l0[c4 + 2] + ev * v3l0[c4 + 2], 0.f) * 0.015625f;
            float v3v = fmaxf(xv * w1l0[c4 + 3] + ev * v3l0[c4 + 3], 0.f) * 0.015625f;
            int u = __builtin_amdgcn_cvt_pk_fp8_f32(v0, v1, 0, false);
            u = __builtin_amdgcn_cvt_pk_fp8_f32(v2, v3v, u, true);
            uchar* dst = (c4 < 64) ? emb0Lo : emb0Hi;
            *(uint32*)(dst + (size_t)n * 64 + (c4 & 63)) = (uint32)u;
        }
    }
}

// ------- gather over PLANAR fp8 emb half-rows (64 B): 1 node/wave, 4 EDGES PER LOAD -------
// Two passes (Lo plane then Hi); each plane is 3.2 MB -> fits per-XCD 4 MiB L2, killing
// the ~41% L2-miss / L3-latency penalty of the monolithic 6.4 MB table (r6 FETCH evidence).
// Quarter-wave (16 lanes x 4 B) covers one 64-B half-row -> 1 dword load / 4 edges.
__global__ __launch_bounds__(256) void k_gather(const uchar* __restrict__ embLo,
                                                const uchar* __restrict__ embHi,
                                                const int* __restrict__ offs,
                                                const int* __restrict__ csr,
                                                uint32* __restrict__ agg) {
    int node = (blockIdx.x * 256 + threadIdx.x) >> 6;
    int lane = threadIdx.x & 63;
    if (node >= N_NODES) return;
    int q  = lane >> 4;                   // quarter 0..3 -> edge j+q
    int ql = lane & 15;                   // lane within quarter
    int boff = ql << 2;                   // byte offset in 64-B half-row
    bool q0 = (q & 1) != 0, q1 = (q & 2) != 0;
    int s = offs[node], e = offs[node + 1];
#pragma unroll 1
    for (int p = 0; p < 2; p++) {
        const uchar* emb = p ? embHi : embLo;
        f32x2 a0 = {0.f, 0.f}, a1 = a0, a2 = a0, a3 = a0;
#pragma unroll 1
        for (int base = s; base < e; base += 64) {
            int idx = base + lane;
            int cv = (idx < e) ? csr[idx] : 0;   // coalesced; L2-hit on 2nd pass/hop
            int cnt = e - base; if (cnt > 64) cnt = 64;
            int j = 0;
#pragma unroll 1
            for (; j + 16 <= cnt; j += 16) {     // 4 loads = 16 edges
                uint32 w[4];
#pragma unroll
                for (int u = 0; u < 4; u++) {
                    int c0 = __builtin_amdgcn_readlane(cv, j + 4 * u + 0);
                    int c1 = __builtin_amdgcn_readlane(cv, j + 4 * u + 1);
                    int c2 = __builtin_amdgcn_readlane(cv, j + 4 * u + 2);
                    int c3 = __builtin_amdgcn_readlane(cv, j + 4 * u + 3);
                    int clo = q0 ? c1 : c0;
                    int chi = q0 ? c3 : c2;
                    int c   = q1 ? chi : clo;
                    w[u] = *(const uint32*)(emb + (((uint32)c) << 6) + boff);
                }
#pragma unroll
                for (int u = 0; u < 4; u++) {
                    f32x2 lo = __builtin_amdgcn_cvt_pk_f32_fp8((int)w[u], false);
                    f32x2 hi = __builtin_amdgcn_cvt_pk_f32_fp8((int)w[u], true);
                    if (u & 1) { a2 += lo; a3 += hi; } else { a0 += lo; a1 += hi; }
                }
            }
#pragma unroll 1
            for (; j < cnt; j += 4) {            // ragged tail, quarters past end add zeros
                int jm = cnt - 1;
                int c0 = __builtin_amdgcn_readlane(cv, j);
                int c1 = __builtin_amdgcn_readlane(cv, (j + 1 < cnt) ? j + 1 : jm);
                int c2 = __builtin_amdgcn_readlane(cv, (j + 2 < cnt) ? j + 2 : jm);
                int c3 = __builtin_amdgcn_readlane(cv, (j + 3 < cnt) ? j + 3 : jm);
                int clo = q0 ? c1 : c0;
                int chi = q0 ? c3 : c2;
                int c   = q1 ? chi : clo;
                uint32 w = *(const uint32*)(emb + (((uint32)c) << 6) + boff);
                if (j + q >= cnt) w = 0u;        // fp8 zero -> exact 0.0
                a0 += __builtin_amdgcn_cvt_pk_f32_fp8((int)w, false);
                a1 += __builtin_amdgcn_cvt_pk_f32_fp8((int)w, true);
            }
        }
        a0 += a2; a1 += a3;
        // cross-quarter reduce: quarters hold identical dim slots
        a0.x += __shfl_xor(a0.x, 16); a0.y += __shfl_xor(a0.y, 16);
        a1.x += __shfl_xor(a1.x, 16); a1.y += __shfl_xor(a1.y, 16);
        a0.x += __shfl_xor(a0.x, 32); a0.y += __shfl_xor(a0.y, 32);
        a1.x += __shfl_xor(a1.x, 32); a1.y += __shfl_xor(a1.y, 32);
        if (lane < 16) {
            uint2 wv2;
            wv2.x = pack_bf16(a0.x * 64.f, a0.y * 64.f);   // dims p*64 + 4ql, +1
            wv2.y = pack_bf16(a1.x * 64.f, a1.y * 64.f);   // dims p*64 + 4ql+2, +3
            *(uint2*)(agg + (size_t)node * 64 + p * 32 + ql * 2) = wv2;
        }
    }
}

#define LROW 136  // padded LDS row, bf16 elems

// ------- MFMA GEMM hop: emb = relu(agg @ W2T + x*w1 + ea*v3) -------
// A-fragments load directly from global (aggB word layout == fragment order).
// !LAST: planar fp8 emb out (scale 2^-6).  LAST: fused W7 head + graph pooling.
template <bool LAST>
__global__ __launch_bounds__(256) void k_gemm(const uint32* __restrict__ agg,   // bf16 [N][64u32]
                                              const ushort* __restrict__ w2p,   // B-frag packed
                                              const float* __restrict__ w1l,
                                              const float* __restrict__ v3l,
                                              const float* __restrict__ x,
                                              const float* __restrict__ ea_sum,
                                              uchar* __restrict__ emb8Lo,       // fp8 plane (!LAST)
                                              uchar* __restrict__ emb8Hi,       // fp8 plane (!LAST)
                                              const ushort* __restrict__ w7p,
                                              const float* __restrict__ W5,
                                              float* __restrict__ outp,
                                              const int* __restrict__ batch,
                                              float* __restrict__ pooled) {
    __shared__ ushort tile[64 * LROW]; // 17408 B (epilogue staging only)
    __shared__ float redp[4][128];     // pooling cross-wave reduce (LAST)
    int tid = threadIdx.x;
    int tbase = blockIdx.x * 64;
    int wv = tid >> 6, lane = tid & 63;
    int n0 = lane & 15, quad = lane >> 4;
    int arow = wv * 16 + n0;
    bf16x8 a0 = {0,0,0,0,0,0,0,0}, a1 = a0, a2 = a0, a3 = a0;
    if (tbase + arow < N_NODES) {
        const bf16x8* ap = (const bf16x8*)(agg + (size_t)(tbase + arow) * 64);
        a0 = ap[0 + quad]; a1 = ap[4 + quad]; a2 = ap[8 + quad]; a3 = ap[12 + quad];
    }
    const bf16x8* wb = (const bf16x8*)w2p;
    f32x4 acc[8];
#pragma unroll
    for (int t = 0; t < 8; t++) {
        f32x4 c = {0.f, 0.f, 0.f, 0.f};
        c = __builtin_amdgcn_mfma_f32_16x16x32_bf16(a0, wb[(t * 4 + 0) * 64 + lane], c, 0, 0, 0);
        c = __builtin_amdgcn_mfma_f32_16x16x32_bf16(a1, wb[(t * 4 + 1) * 64 + lane], c, 0, 0, 0);
        c = __builtin_amdgcn_mfma_f32_16x16x32_bf16(a2, wb[(t * 4 + 2) * 64 + lane], c, 0, 0, 0);
        c = __builtin_amdgcn_mfma_f32_16x16x32_bf16(a3, wb[(t * 4 + 3) * 64 + lane], c, 0, 0, 0);
        acc[t] = c;
    }
    float xs[4], es[4];
#pragma unroll
    for (int r = 0; r < 4; r++) {
        int n = tbase + wv * 16 + quad * 4 + r;
        xs[r] = (n < N_NODES) ? x[n] : 0.f;
        es[r] = (n < N_NODES) ? ea_sum[n] : 0.f;
    }
    if (!LAST) {
        // epilogue: planar fp8 output, scale 2^-6 (exact pow2; rescaled x64 in k_gather)
        uchar* stile = (uchar*)tile;   // rows stride 136 B; wave-private rows
#pragma unroll
        for (int t = 0; t < 8; t++) {
            int hp = t * 16 + n0;
            float w1v = w1l[hp], v3v = v3l[hp];
#pragma unroll
            for (int r = 0; r < 4; r++) {
                float v = fmaxf(acc[t][r] + xs[r] * w1v + es[r] * v3v, 0.f) * 0.015625f;
                int enc = __builtin_amdgcn_cvt_pk_fp8_f32(v, v, 0, false);
                stile[(wv * 16 + quad * 4 + r) * 136 + hp] = (uchar)(enc & 0xff);
            }
        }
        __syncthreads();
        int vn = N_NODES - tbase; if (vn > 64) vn = 64;
        for (int i = tid; i < 64 * 32; i += 256) {
            int r = i >> 5, c4 = (i & 31) * 4;
            if (r < vn) {
                uint32 u = *(const uint32*)&stile[r * 136 + c4];
                uchar* dst = (c4 < 64) ? emb8Lo : emb8Hi;
                *(uint32*)(dst + (size_t)(tbase + r) * 64 + (c4 & 63)) = u;
            }
        }
    } else {
        // epilogue: bf16 through LDS for W7 head; fused graph pooling
        int nlast = tbase + 63; if (nlast > N_NODES - 1) nlast = N_NODES - 1;
        int g0 = batch[tbase];
        bool uni = (batch[nlast] == g0);           // block-uniform
        int gr[4];
        if (!uni) {
#pragma unroll
            for (int r = 0; r < 4; r++) {
                int n = tbase + wv * 16 + quad * 4 + r;
                gr[r] = (n < N_NODES) ? batch[n] : 0;
            }
        }
        float st[8];
#pragma unroll
        for (int t = 0; t < 8; t++) {
            int hp = t * 16 + n0;
            float w1v = w1l[hp], v3v = v3l[hp];
            float stt = 0.f;
#pragma unroll
            for (int r = 0; r < 4; r++) {
                float v = fmaxf(acc[t][r] + xs[r] * w1v + es[r] * v3v, 0.f);
                tile[(wv * 16 + quad * 4 + r) * LROW + hp] = (ushort)bf16r(v);
                if (uni) {
                    stt += v;   // invalid rows contribute exactly 0 (zeroed frags + xs/es)
                } else {
                    int n = tbase + wv * 16 + quad * 4 + r;
                    if (n < N_NODES) atomicAdd(&pooled[gr[r] * HID + hp], v);
                }
            }
            st[t] = stt;
        }
        if (uni) {
#pragma unroll
            for (int t = 0; t < 8; t++) {
                float v = st[t];
                v += __shfl_xor(v, 16);
                v += __shfl_xor(v, 32);
                if (lane < 16) redp[wv][t * 16 + lane] = v;
            }
        }
        __syncthreads();
        if (uni && tid < 128) {
            float sp = (redp[0][tid] + redp[1][tid]) + (redp[2][tid] + redp[3][tid]);
            atomicAdd(&pooled[g0 * HID + tid], sp);
        }
        bf16x8 b0 = *(const bf16x8*)&tile[arow * LROW + 0 * 32 + quad * 8];
        bf16x8 b1 = *(const bf16x8*)&tile[arow * LROW + 1 * 32 + quad * 8];
        bf16x8 b2 = *(const bf16x8*)&tile[arow * LROW + 2 * 32 + quad * 8];
        bf16x8 b3 = *(const bf16x8*)&tile[arow * LROW + 3 * 32 + quad * 8];
        const bf16x8* w7 = (const bf16x8*)w7p;
        float p[4] = {0.f, 0.f, 0.f, 0.f};
#pragma unroll
        for (int t = 0; t < 8; t++) {
            f32x4 c = {0.f, 0.f, 0.f, 0.f};
            c = __builtin_amdgcn_mfma_f32_16x16x32_bf16(b0, w7[(t * 4 + 0) * 64 + lane], c, 0, 0, 0);
            c = __builtin_amdgcn_mfma_f32_16x16x32_bf16(b1, w7[(t * 4 + 1) * 64 + lane], c, 0, 0, 0);
            c = __builtin_amdgcn_mfma_f32_16x16x32_bf16(b2, w7[(t * 4 + 2) * 64 + lane], c, 0, 0, 0);
            c = __builtin_amdgcn_mfma_f32_16x16x32_bf16(b3, w7[(t * 4 + 3) * 64 + lane], c, 0, 0, 0);
            float w5v = W5[128 + t * 16 + n0];
#pragma unroll
            for (int r = 0; r < 4; r++) p[r] += fmaxf(c[r], 0.f) * w5v;
        }
#pragma unroll
        for (int r = 0; r < 4; r++) {
            float v = p[r];
            v += __shfl_xor(v, 1);
            v += __shfl_xor(v, 2);
            v += __shfl_xor(v, 4);
            v += __shfl_xor(v, 8);
            int n = tbase + wv * 16 + quad * 4 + r;
            if (n0 == 0 && n < N_NODES) outp[n] = v;
        }
    }
}

// ------- tail (fused k_graph + k_addsg): per-block compute the <=2 needed s_g, add -------
__global__ __launch_bounds__(256) void k_tail(float* __restrict__ out,
                                              const int* __restrict__ batch,
                                              const float* __restrict__ pooled,
                                              const float* __restrict__ W6,
                                              const float* __restrict__ W5,
                                              const float* __restrict__ b5) {
    __shared__ float red[256];
    __shared__ int gsh[2];
    int t = threadIdx.x;
    int nbase = blockIdx.x * 256;
    int n = nbase + t;
    if (t == 0) gsh[0] = batch[nbase < N_NODES ? nbase : N_NODES - 1];
    if (t == 1) gsh[1] = batch[(nbase + 255) < N_NODES ? (nbase + 255) : N_NODES - 1];
    __syncthreads();
    int g_lo = gsh[0], g_hi = gsh[1];
    int hp = t & 127;
    int g = (t >> 7) ? g_hi : g_lo;
    const float* pg = pooled + g * HID;
    const float* wr = W6 + hp * HID;
    float acc = 0.f;
    for (int h = 0; h < HID; h++) acc += pg[h] * wr[h];
    red[t] = fmaxf(acc, 0.f) * W5[hp];
    __syncthreads();
    for (int d = 64; d > 0; d >>= 1) {
        if (hp < d) red[t] += red[t + d];
        __syncthreads();
    }
    float s_lo = red[0], s_hi = red[128];
    if (n < N_NODES) {
        int gn = batch[n];
        float s;
        if (gn == g_lo) s = s_lo;
        else if (gn == g_hi) s = s_hi;
        else {   // middle graph inside one 256-block: impossible for this input, kept for safety
            s = 0.f;
            const float* pg2 = pooled + gn * HID;
            for (int hp2 = 0; hp2 < HID; hp2++) {
                float a2 = 0.f;
                for (int h = 0; h < HID; h++) a2 += pg2[h] * W6[hp2 * HID + h];
                s += fmaxf(a2, 0.f) * W5[hp2];
            }
        }
        out[n] += s + b5[0];
    }
}

extern "C" void kernel_launch(void* const* d_in, const int* in_sizes, int n_in,
                              void* d_out, int out_size, void* d_ws, size_t ws_size,
                              hipStream_t stream) {
    (void)in_sizes; (void)n_in; (void)out_size; (void)ws_size;
    const float* x    = (const float*)d_in[0];
    const int*   ei   = (const int*)d_in[1];   // [2,E] flat: row then col
    const float* ea   = (const float*)d_in[2];
    const int*   bat  = (const int*)d_in[3];
    const float* W1   = (const float*)d_in[4]; // [3,128,1]
    const float* W2   = (const float*)d_in[5]; // [3,128,128]
    const float* W3   = (const float*)d_in[6];
    const float* W4   = (const float*)d_in[7]; // [3,128,1]
    const float* W5   = (const float*)d_in[8]; // [1,256]
    const float* b5   = (const float*)d_in[9];
    const float* W6   = (const float*)d_in[10];
    const float* W7   = (const float*)d_in[11];
    float* out = (float*)d_out;

    const int* row = ei;
    const int* col = ei + N_EDGES;

    // workspace layout (4B elems)
    float* wsf = (float*)d_ws;
    int*   wsi = (int*)d_ws;
    size_t o = 0;
    float* pooled = wsf + o; o += NGRAPH * HID;     // zeroed (atomic target)
    size_t ztot = o;                                // 2048
    int*   offs   = wsi + o; o += N_NODES + 1;
    float* ea_sum = wsf + o; o += N_NODES;
    int*   btot   = wsi + o; o += NB;
    float* v3     = wsf + o; o += 3 * HID;
    int*   blkh   = wsi + o; o += NB * NBLK;
    o = (o + 3) & ~(size_t)3;
    ushort* wpack = (ushort*)(wsi + o); o += 4 * 16384 / 2;
    int*    csr   = wsi + o; o += N_EDGES;
    o = (o + 1) & ~(size_t)1;
    int2*   pea   = (int2*)(wsi + o); o += 2 * (size_t)N_EDGES;
    uint32* aggB  = (uint32*)(wsi + o); o += (size_t)N_NODES * 64;  // bf16 [N][128], frag order
    uchar*  emb8Lo = (uchar*)(wsi + o); o += (size_t)N_NODES * 16;  // fp8 plane [N][64B]
    uchar*  emb8Hi = (uchar*)(wsi + o); o += (size_t)N_NODES * 16;
    uchar*  emb0Lo = (uchar*)(wsi + o); o += (size_t)N_NODES * 16;
    uchar*  emb0Hi = (uchar*)(wsi + o); o += (size_t)N_NODES * 16;

    const ushort* w2p1 = wpack + 1 * 16384;
    const ushort* w2p2 = wpack + 2 * 16384;
    const ushort* w7p  = wpack + 3 * 16384;

    // 1) histogram + fused init (zero pooled, weight prep, v3)
    k_p1i<<<NBLK, 1024, 0, stream>>>(row, blkh, (float*)d_ws, (int)ztot,
                                     W2, W7, W3, W4, (ushort*)wpack, v3);
    // 2) CSR build; p4 also materializes emb0 planes (fp8 layer-0 embeddings)
    k_p2a<<<NB, NBLK, 0, stream>>>(blkh, btot);
    k_p3_part<<<NBLK, 1024, 0, stream>>>(row, col, ea, blkh, btot, pea);
    k_p4<<<NB, 512, 0, stream>>>(pea, btot, x, offs, ea_sum, csr, emb0Lo, emb0Hi, W1, v3);
    // 3) hop 1: planar 2-pass gather (emb0) -> MFMA gemm -> emb8 planes
    k_gather<<<(N_NODES * 64 + 255) / 256, 256, 0, stream>>>(emb0Lo, emb0Hi, offs, csr, aggB);
    k_gemm<false><<<(N_NODES + 63) / 64, 256, 0, stream>>>(
        aggB, w2p1, W1 + 1 * HID, v3 + 1 * HID, x, ea_sum, emb8Lo, emb8Hi,
        nullptr, nullptr, nullptr, nullptr, nullptr);
    // 4) hop 2: planar gather (emb8) -> MFMA gemm + W7 head + fused pooling
    k_gather<<<(N_NODES * 64 + 255) / 256, 256, 0, stream>>>(emb8Lo, emb8Hi, offs, csr, aggB);
    k_gemm<true><<<(N_NODES + 63) / 64, 256, 0, stream>>>(
        aggB, w2p2, W1 + 2 * HID, v3 + 2 * HID, x, ea_sum, nullptr, nullptr,
        w7p, W5, out, bat, pooled);
    // 5) tail: per-graph scalar + bias add (fused)
    k_tail<<<(N_NODES + 255) / 256, 256, 0, stream>>>(out, bat, pooled, W6, W5, b5);
}

// Round 12
// 258.552 us; speedup vs baseline: 1.1333x; 1.1333x over previous
//
#include <hip/hip_runtime.h>
#include <hip/hip_bf16.h>

#define N_NODES 50000
#define N_EDGES 1600000
#define NGRAPH  16
#define HID     128

#define RPB   128                           // rows per bucket
#define NB    ((N_NODES + RPB - 1) / RPB)   // 391 buckets
#define NBLK  256                           // partition blocks
#define EPB   ((N_EDGES + NBLK - 1) / NBLK) // 6250 edges per partition block
#define P4CAP 6144                          // LDS cache entries for a bucket run (mean 4092, sd 64)

typedef unsigned int uint32;
typedef unsigned short ushort;
typedef unsigned char uchar;
typedef __attribute__((ext_vector_type(8))) short bf16x8;
typedef __attribute__((ext_vector_type(4))) float f32x4;
typedef __attribute__((ext_vector_type(2))) float f32x2;

// bf16 round-to-nearest-even helpers
__device__ __forceinline__ uint32 bf16r(float f) {
    uint32 b = __float_as_uint(f);
    return (b + 0x7fffu + ((b >> 16) & 1u)) >> 16;
}
__device__ __forceinline__ uint32 pack_bf16(float lo, float hi) {
    return bf16r(lo) | (bf16r(hi) << 16);
}

// ---------------- init: zero pooled + weight prep (W2/W7 B-frag pack, v3) ----------------
__global__ __launch_bounds__(256) void k_init(float* __restrict__ zp, int nz,
                                              const float* __restrict__ W2,
                                              const float* __restrict__ W7,
                                              const float* __restrict__ W3,
                                              const float* __restrict__ W4,
                                              ushort* __restrict__ wpack,
                                              float* __restrict__ v3) {
    int idx = blockIdx.x * 256 + threadIdx.x;
    if (idx < nz) zp[idx] = 0.f;
    if (idx < 4 * 16384) {
        int m = idx >> 14, f = idx & 16383;
        int j = f & 7, lane = (f >> 3) & 63, kk = (f >> 9) & 3, t = (f >> 11) & 7;
        int hp = t * 16 + (lane & 15);
        int k  = kk * 32 + ((lane >> 4) & 3) * 8 + j;
        const float* src = (m < 3) ? (W2 + m * HID * HID) : W7;
        wpack[idx] = (ushort)bf16r(src[hp * HID + k]);
    }
    if (idx < 3 * HID) {
        int l = idx / HID, hp = idx % HID;
        float acc = 0.f;
        for (int h = 0; h < HID; h++)
            acc += W3[l * HID * HID + hp * HID + h] * fmaxf(W4[l * HID + h], 0.f);
        v3[idx] = acc;
    }
}

// ---------------- P1: per-(bucket,block) histogram ----------------
__global__ __launch_bounds__(1024) void k_p1_hist(const int* __restrict__ row,
                                                  int* __restrict__ blkhist) {
    __shared__ int hist[NB];
    int tid = threadIdx.x, blk = blockIdx.x;
    for (int i = tid; i < NB; i += 1024) hist[i] = 0;
    __syncthreads();
    int s = blk * EPB, e = s + EPB; if (e > N_EDGES) e = N_EDGES;
    for (int i = s + tid; i < e; i += 1024)
        atomicAdd(&hist[row[i] >> 7], 1);
    __syncthreads();
    for (int i = tid; i < NB; i += 1024)
        blkhist[i * NBLK + blk] = hist[i];
}

// ------- P2a: per-bucket exclusive scan over its NBLK per-block counts -------
__global__ __launch_bounds__(NBLK) void k_p2a(int* __restrict__ blkhist,
                                              int* __restrict__ btot) {
    __shared__ int sums[NBLK];
    int t = threadIdx.x, b = blockIdx.x;
    int v = blkhist[b * NBLK + t];
    sums[t] = v;
    __syncthreads();
    for (int d = 1; d < NBLK; d <<= 1) {
        int u = (t >= d) ? sums[t - d] : 0;
        __syncthreads();
        sums[t] += u;
        __syncthreads();
    }
    blkhist[b * NBLK + t] = sums[t] - v;     // local exclusive
    if (t == NBLK - 1) btot[b] = sums[t];    // bucket total
}

// ------- P3: scatter int2{rowlocal:8|col:16, ea} into bucket runs -------
// (bucket bases recomputed per-block from btot via LDS scan)
__global__ __launch_bounds__(1024) void k_p3_part(const int* __restrict__ row,
                                                  const int* __restrict__ col,
                                                  const float* __restrict__ ea,
                                                  const int* __restrict__ blkhist,
                                                  const int* __restrict__ btot,
                                                  int2* __restrict__ pea) {
    __shared__ int sc[512];
    __shared__ int cur[NB];
    int tid = threadIdx.x, blk = blockIdx.x;
    if (tid < 512) sc[tid] = (tid < NB) ? btot[tid] : 0;
    __syncthreads();
    for (int d = 1; d < 512; d <<= 1) {
        int v = 0;
        if (tid < 512 && tid >= d) v = sc[tid - d];
        __syncthreads();
        if (tid < 512) sc[tid] += v;
        __syncthreads();
    }
    for (int i = tid; i < NB; i += 1024)
        cur[i] = (sc[i] - btot[i]) + blkhist[i * NBLK + blk];
    __syncthreads();
    int s = blk * EPB, e = s + EPB; if (e > N_EDGES) e = N_EDGES;
    for (int i = s + tid; i < e; i += 1024) {
        int r = row[i], c = col[i];
        float a = ea[i];
        int slot = atomicAdd(&cur[r >> 7], 1);
        pea[slot] = make_int2(((r & (RPB - 1)) << 16) | c, __float_as_int(a));
    }
}

// ------- P4: bucket run staged in LDS once; counts+scan -> offs/ea_sum, scatter csr,
//         and materialize emb0[n] = relu(x[n]*w1 + ea_sum[n]*v3) as fp8 rows (scale 2^-6). -------
__global__ __launch_bounds__(512) void k_p4(const int2* __restrict__ pea,
                                            const int* __restrict__ btot,
                                            const float* __restrict__ x,
                                            int* __restrict__ offs,
                                            float* __restrict__ ea_sum,
                                            int* __restrict__ csr,
                                            uchar* __restrict__ emb0,
                                            const float* __restrict__ w1l0,
                                            const float* __restrict__ v3l0) {
    __shared__ int2  cache[P4CAP];   // 48 KB
    __shared__ int   red[512];
    __shared__ int   cnt[RPB];
    __shared__ float eas[RPB];
    __shared__ int   scan_s[RPB];
    __shared__ int   curp[RPB];
    int t = threadIdx.x, b = blockIdx.x;
    // bucket base s = sum(btot[0..b)), e = s + btot[b]
    red[t] = (t < b) ? btot[t] : 0;          // t<b implies t<NB
    __syncthreads();
    for (int d = 256; d > 0; d >>= 1) {
        if (t < d) red[t] += red[t + d];
        __syncthreads();
    }
    int s = red[0];
    int e = s + btot[b];
    int len = e - s;
    int clen = len < P4CAP ? len : P4CAP;    // statistical bound: len never exceeds P4CAP
    for (int i = t; i < clen; i += 512) cache[i] = pea[s + i];
    if (t < RPB) { cnt[t] = 0; eas[t] = 0.f; }
    __syncthreads();
    // pass 1: per-node counts + ea sums
    for (int i = t; i < len; i += 512) {
        int2 p = (i < P4CAP) ? cache[i] : pea[s + i];
        int lr = ((uint32)p.x) >> 16;
        atomicAdd(&cnt[lr], 1);
        atomicAdd(&eas[lr], __int_as_float(p.y));
    }
    __syncthreads();
    if (t < RPB) scan_s[t] = cnt[t];
    __syncthreads();
    for (int d = 1; d < RPB; d <<= 1) {
        int v = 0;
        if (t < RPB && t >= d) v = scan_s[t - d];
        __syncthreads();
        if (t < RPB) scan_s[t] += v;
        __syncthreads();
    }
    int nbase = b * RPB;
    if (t < RPB) {
        int excl = scan_s[t] - cnt[t];
        int n = nbase + t;
        if (n < N_NODES) {
            offs[n] = s + excl;
            ea_sum[n] = eas[t];
        }
        curp[t] = s + excl;
    }
    if (b == NB - 1 && t == 0) offs[N_NODES] = e;
    __syncthreads();
    // pass 2: scatter csr from the LDS-cached run
    for (int i = t; i < len; i += 512) {
        int2 p = (i < P4CAP) ? cache[i] : pea[s + i];
        int slot = atomicAdd(&curp[((uint32)p.x) >> 16], 1);
        csr[slot] = p.x & 0xFFFF;
    }
    // epilogue: emb0 fp8 rows for this bucket's 128 nodes (coalesced 16 KB write)
    for (int i = t; i < RPB * 32; i += 512) {
        int lr = i >> 5, c4 = (i & 31) * 4;
        int n = nbase + lr;
        if (n < N_NODES) {
            float xv = x[n];
            float ev = eas[lr];
            float v0 = fmaxf(xv * w1l0[c4 + 0] + ev * v3l0[c4 + 0], 0.f) * 0.015625f;
            float v1 = fmaxf(xv * w1l0[c4 + 1] + ev * v3l0[c4 + 1], 0.f) * 0.015625f;
            float v2 = fmaxf(xv * w1l0[c4 + 2] + ev * v3l0[c4 + 2], 0.f) * 0.015625f;
            float v3v = fmaxf(xv * w1l0[c4 + 3] + ev * v3l0[c4 + 3], 0.f) * 0.015625f;
            int u = __builtin_amdgcn_cvt_pk_fp8_f32(v0, v1, 0, false);
            u = __builtin_amdgcn_cvt_pk_fp8_f32(v2, v3v, u, true);
            *(uint32*)(emb0 + (size_t)n * 128 + c4) = (uint32)u;
        }
    }
}

// ------- gather over fp8 emb rows (128 B): 1 node/wave, 2 B/lane (best-verified shape) -------
// readlane (compile-time lane idx) -> scalar neighbor index -> SGPR-based row address;
// 16-deep load pipeline for L2 latency hiding. Used for BOTH hops.
__global__ __launch_bounds__(256) void k_gather(const uchar* __restrict__ emb,
                                                const int* __restrict__ offs,
                                                const int* __restrict__ csr,
                                                uint32* __restrict__ agg) {
    int node = (blockIdx.x * 256 + threadIdx.x) >> 6;
    int lane = threadIdx.x & 63;
    if (node >= N_NODES) return;
    int s = offs[node], e = offs[node + 1];
    int off2 = 2 * lane;
    float ax[8] = {0.f}, ay[8] = {0.f};
    for (int base = s; base < e; base += 64) {
        int idx = base + lane;
        int cv = (idx < e) ? csr[idx] : 0;     // one coalesced load per 64 edges
        int cnt = e - base; if (cnt > 64) cnt = 64;
        int j = 0;
        for (; j + 16 <= cnt; j += 16) {
            int h16[16];
#pragma unroll
            for (int u = 0; u < 16; u++) {
                uint32 c = (uint32)__builtin_amdgcn_readlane(cv, j + u);  // SGPR index
                h16[u] = *(const ushort*)(emb + (((size_t)c) << 7) + off2);
            }
#pragma unroll
            for (int u = 0; u < 16; u++) {
                f32x2 d = __builtin_amdgcn_cvt_pk_f32_fp8(h16[u], false);
                ax[u & 7] += d.x; ay[u & 7] += d.y;
            }
        }
        for (; j + 4 <= cnt; j += 4) {
            int h4[4];
#pragma unroll
            for (int u = 0; u < 4; u++) {
                uint32 c = (uint32)__builtin_amdgcn_readlane(cv, j + u);
                h4[u] = *(const ushort*)(emb + (((size_t)c) << 7) + off2);
            }
#pragma unroll
            for (int u = 0; u < 4; u++) {
                f32x2 d = __builtin_amdgcn_cvt_pk_f32_fp8(h4[u], false);
                ax[u] += d.x; ay[u] += d.y;
            }
        }
        for (; j < cnt; j++) {
            uint32 c = (uint32)__builtin_amdgcn_readlane(cv, j);
            int h = *(const ushort*)(emb + (((size_t)c) << 7) + off2);
            f32x2 d = __builtin_amdgcn_cvt_pk_f32_fp8(h, false);
            ax[0] += d.x; ay[0] += d.y;
        }
    }
    float rx = (((ax[0] + ax[1]) + (ax[2] + ax[3])) + ((ax[4] + ax[5]) + (ax[6] + ax[7]))) * 64.f;
    float ry = (((ay[0] + ay[1]) + (ay[2] + ay[3])) + ((ay[4] + ay[5]) + (ay[6] + ay[7]))) * 64.f;
    agg[(size_t)node * 64 + lane] = pack_bf16(rx, ry);
}

#define LROW 136  // padded LDS row, bf16 elems

// ------- MFMA GEMM hop: emb = relu(agg @ W2T + x*w1 + ea*v3) -------
// A-fragments load directly from global (aggB word layout == fragment order).
// !LAST: fp8 emb out (scale 2^-6).  LAST: fused W7 head + graph pooling.
template <bool LAST>
__global__ __launch_bounds__(256) void k_gemm(const uint32* __restrict__ agg,   // bf16 [N][64u32]
                                              const ushort* __restrict__ w2p,   // B-frag packed
                                              const float* __restrict__ w1l,
                                              const float* __restrict__ v3l,
                                              const float* __restrict__ x,
                                              const float* __restrict__ ea_sum,
                                              uchar* __restrict__ emb8Out,      // fp8 (!LAST)
                                              const ushort* __restrict__ w7p,
                                              const float* __restrict__ W5,
                                              float* __restrict__ outp,
                                              const int* __restrict__ batch,
                                              float* __restrict__ pooled) {
    __shared__ ushort tile[64 * LROW]; // 17408 B (epilogue staging only)
    __shared__ float redp[4][128];     // pooling cross-wave reduce (LAST)
    int tid = threadIdx.x;
    int tbase = blockIdx.x * 64;
    int wv = tid >> 6, lane = tid & 63;
    int n0 = lane & 15, quad = lane >> 4;
    int arow = wv * 16 + n0;
    bf16x8 a0 = {0,0,0,0,0,0,0,0}, a1 = a0, a2 = a0, a3 = a0;
    if (tbase + arow < N_NODES) {
        const bf16x8* ap = (const bf16x8*)(agg + (size_t)(tbase + arow) * 64);
        a0 = ap[0 + quad]; a1 = ap[4 + quad]; a2 = ap[8 + quad]; a3 = ap[12 + quad];
    }
    const bf16x8* wb = (const bf16x8*)w2p;
    f32x4 acc[8];
#pragma unroll
    for (int t = 0; t < 8; t++) {
        f32x4 c = {0.f, 0.f, 0.f, 0.f};
        c = __builtin_amdgcn_mfma_f32_16x16x32_bf16(a0, wb[(t * 4 + 0) * 64 + lane], c, 0, 0, 0);
        c = __builtin_amdgcn_mfma_f32_16x16x32_bf16(a1, wb[(t * 4 + 1) * 64 + lane], c, 0, 0, 0);
        c = __builtin_amdgcn_mfma_f32_16x16x32_bf16(a2, wb[(t * 4 + 2) * 64 + lane], c, 0, 0, 0);
        c = __builtin_amdgcn_mfma_f32_16x16x32_bf16(a3, wb[(t * 4 + 3) * 64 + lane], c, 0, 0, 0);
        acc[t] = c;
    }
    float xs[4], es[4];
#pragma unroll
    for (int r = 0; r < 4; r++) {
        int n = tbase + wv * 16 + quad * 4 + r;
        xs[r] = (n < N_NODES) ? x[n] : 0.f;
        es[r] = (n < N_NODES) ? ea_sum[n] : 0.f;
    }
    if (!LAST) {
        // epilogue: fp8 output, scale 2^-6 (exact pow2; rescaled x64 in k_gather)
        uchar* stile = (uchar*)tile;   // rows stride 136 B; wave-private rows
#pragma unroll
        for (int t = 0; t < 8; t++) {
            int hp = t * 16 + n0;
            float w1v = w1l[hp], v3v = v3l[hp];
#pragma unroll
            for (int r = 0; r < 4; r++) {
                float v = fmaxf(acc[t][r] + xs[r] * w1v + es[r] * v3v, 0.f) * 0.015625f;
                int enc = __builtin_amdgcn_cvt_pk_fp8_f32(v, v, 0, false);
                stile[(wv * 16 + quad * 4 + r) * 136 + hp] = (uchar)(enc & 0xff);
            }
        }
        __syncthreads();
        int vn = N_NODES - tbase; if (vn > 64) vn = 64;
        for (int i = tid; i < 64 * 32; i += 256) {
            int r = i >> 5, c4 = (i & 31) * 4;
            if (r < vn) {
                uint32 u = *(const uint32*)&stile[r * 136 + c4];
                *(uint32*)(emb8Out + (size_t)(tbase + r) * 128 + c4) = u;
            }
        }
    } else {
        // epilogue: bf16 through LDS for W7 head; fused graph pooling
        int nlast = tbase + 63; if (nlast > N_NODES - 1) nlast = N_NODES - 1;
        int g0 = batch[tbase];
        bool uni = (batch[nlast] == g0);           // block-uniform
        int gr[4];
        if (!uni) {
#pragma unroll
            for (int r = 0; r < 4; r++) {
                int n = tbase + wv * 16 + quad * 4 + r;
                gr[r] = (n < N_NODES) ? batch[n] : 0;
            }
        }
        float st[8];
#pragma unroll
        for (int t = 0; t < 8; t++) {
            int hp = t * 16 + n0;
            float w1v = w1l[hp], v3v = v3l[hp];
            float stt = 0.f;
#pragma unroll
            for (int r = 0; r < 4; r++) {
                float v = fmaxf(acc[t][r] + xs[r] * w1v + es[r] * v3v, 0.f);
                tile[(wv * 16 + quad * 4 + r) * LROW + hp] = (ushort)bf16r(v);
                if (uni) {
                    stt += v;   // invalid rows contribute exactly 0 (zeroed frags + xs/es)
                } else {
                    int n = tbase + wv * 16 + quad * 4 + r;
                    if (n < N_NODES) atomicAdd(&pooled[gr[r] * HID + hp], v);
                }
            }
            st[t] = stt;
        }
        if (uni) {
#pragma unroll
            for (int t = 0; t < 8; t++) {
                float v = st[t];
                v += __shfl_xor(v, 16);
                v += __shfl_xor(v, 32);
                if (lane < 16) redp[wv][t * 16 + lane] = v;
            }
        }
        __syncthreads();
        if (uni && tid < 128) {
            float sp = (redp[0][tid] + redp[1][tid]) + (redp[2][tid] + redp[3][tid]);
            atomicAdd(&pooled[g0 * HID + tid], sp);
        }
        bf16x8 b0 = *(const bf16x8*)&tile[arow * LROW + 0 * 32 + quad * 8];
        bf16x8 b1 = *(const bf16x8*)&tile[arow * LROW + 1 * 32 + quad * 8];
        bf16x8 b2 = *(const bf16x8*)&tile[arow * LROW + 2 * 32 + quad * 8];
        bf16x8 b3 = *(const bf16x8*)&tile[arow * LROW + 3 * 32 + quad * 8];
        const bf16x8* w7 = (const bf16x8*)w7p;
        float p[4] = {0.f, 0.f, 0.f, 0.f};
#pragma unroll
        for (int t = 0; t < 8; t++) {
            f32x4 c = {0.f, 0.f, 0.f, 0.f};
            c = __builtin_amdgcn_mfma_f32_16x16x32_bf16(b0, w7[(t * 4 + 0) * 64 + lane], c, 0, 0, 0);
            c = __builtin_amdgcn_mfma_f32_16x16x32_bf16(b1, w7[(t * 4 + 1) * 64 + lane], c, 0, 0, 0);
            c = __builtin_amdgcn_mfma_f32_16x16x32_bf16(b2, w7[(t * 4 + 2) * 64 + lane], c, 0, 0, 0);
            c = __builtin_amdgcn_mfma_f32_16x16x32_bf16(b3, w7[(t * 4 + 3) * 64 + lane], c, 0, 0, 0);
            float w5v = W5[128 + t * 16 + n0];
#pragma unroll
            for (int r = 0; r < 4; r++) p[r] += fmaxf(c[r], 0.f) * w5v;
        }
#pragma unroll
        for (int r = 0; r < 4; r++) {
            float v = p[r];
            v += __shfl_xor(v, 1);
            v += __shfl_xor(v, 2);
            v += __shfl_xor(v, 4);
            v += __shfl_xor(v, 8);
            int n = tbase + wv * 16 + quad * 4 + r;
            if (n0 == 0 && n < N_NODES) outp[n] = v;
        }
    }
}

// ------- tail (fused k_graph + k_addsg): per-block compute the <=2 needed s_g, add -------
__global__ __launch_bounds__(256) void k_tail(float* __restrict__ out,
                                              const int* __restrict__ batch,
                                              const float* __restrict__ pooled,
                                              const float* __restrict__ W6,
                                              const float* __restrict__ W5,
                                              const float* __restrict__ b5) {
    __shared__ float red[256];
    __shared__ int gsh[2];
    int t = threadIdx.x;
    int nbase = blockIdx.x * 256;
    int n = nbase + t;
    if (t == 0) gsh[0] = batch[nbase < N_NODES ? nbase : N_NODES - 1];
    if (t == 1) gsh[1] = batch[(nbase + 255) < N_NODES ? (nbase + 255) : N_NODES - 1];
    __syncthreads();
    int g_lo = gsh[0], g_hi = gsh[1];
    int hp = t & 127;
    int g = (t >> 7) ? g_hi : g_lo;
    const float* pg = pooled + g * HID;
    const float* wr = W6 + hp * HID;
    float acc = 0.f;
    for (int h = 0; h < HID; h++) acc += pg[h] * wr[h];
    red[t] = fmaxf(acc, 0.f) * W5[hp];
    __syncthreads();
    for (int d = 64; d > 0; d >>= 1) {
        if (hp < d) red[t] += red[t + d];
        __syncthreads();
    }
    float s_lo = red[0], s_hi = red[128];
    if (n < N_NODES) {
        int gn = batch[n];
        float s;
        if (gn == g_lo) s = s_lo;
        else if (gn == g_hi) s = s_hi;
        else {   // middle graph inside one 256-block: impossible for this input, kept for safety
            s = 0.f;
            const float* pg2 = pooled + gn * HID;
            for (int hp2 = 0; hp2 < HID; hp2++) {
                float a2 = 0.f;
                for (int h = 0; h < HID; h++) a2 += pg2[h] * W6[hp2 * HID + h];
                s += fmaxf(a2, 0.f) * W5[hp2];
            }
        }
        out[n] += s + b5[0];
    }
}

extern "C" void kernel_launch(void* const* d_in, const int* in_sizes, int n_in,
                              void* d_out, int out_size, void* d_ws, size_t ws_size,
                              hipStream_t stream) {
    (void)in_sizes; (void)n_in; (void)out_size; (void)ws_size;
    const float* x    = (const float*)d_in[0];
    const int*   ei   = (const int*)d_in[1];   // [2,E] flat: row then col
    const float* ea   = (const float*)d_in[2];
    const int*   bat  = (const int*)d_in[3];
    const float* W1   = (const float*)d_in[4]; // [3,128,1]
    const float* W2   = (const float*)d_in[5]; // [3,128,128]
    const float* W3   = (const float*)d_in[6];
    const float* W4   = (const float*)d_in[7]; // [3,128,1]
    const float* W5   = (const float*)d_in[8]; // [1,256]
    const float* b5   = (const float*)d_in[9];
    const float* W6   = (const float*)d_in[10];
    const float* W7   = (const float*)d_in[11];
    float* out = (float*)d_out;

    const int* row = ei;
    const int* col = ei + N_EDGES;

    // workspace layout (4B elems)
    float* wsf = (float*)d_ws;
    int*   wsi = (int*)d_ws;
    size_t o = 0;
    float* pooled = wsf + o; o += NGRAPH * HID;     // zeroed (atomic target)
    size_t ztot = o;                                // 2048
    int*   offs   = wsi + o; o += N_NODES + 1;
    float* ea_sum = wsf + o; o += N_NODES;
    int*   btot   = wsi + o; o += NB;
    float* v3     = wsf + o; o += 3 * HID;
    int*   blkh   = wsi + o; o += NB * NBLK;
    o = (o + 3) & ~(size_t)3;
    ushort* wpack = (ushort*)(wsi + o); o += 4 * 16384 / 2;
    int*    csr   = wsi + o; o += N_EDGES;
    o = (o + 1) & ~(size_t)1;
    int2*   pea   = (int2*)(wsi + o); o += 2 * (size_t)N_EDGES;
    uint32* aggB  = (uint32*)(wsi + o); o += (size_t)N_NODES * 64;  // bf16 [N][128], frag order
    uchar*  emb8  = (uchar*)(wsi + o);  o += (size_t)N_NODES * 32;  // fp8  [N][128] hop-2 emb
    uchar*  emb0  = (uchar*)(wsi + o);  o += (size_t)N_NODES * 32;  // fp8  [N][128] hop-1 emb

    const ushort* w2p1 = wpack + 1 * 16384;
    const ushort* w2p2 = wpack + 2 * 16384;
    const ushort* w7p  = wpack + 3 * 16384;

    // 0) zero pooled + weight prep (fused)
    k_init<<<(4 * 16384 + 255) / 256, 256, 0, stream>>>(
        (float*)d_ws, (int)ztot, W2, W7, W3, W4, (ushort*)wpack, v3);
    // 1) atomic-free CSR build; p4 also materializes emb0 (fp8 layer-0 embeddings)
    k_p1_hist<<<NBLK, 1024, 0, stream>>>(row, blkh);
    k_p2a<<<NB, NBLK, 0, stream>>>(blkh, btot);
    k_p3_part<<<NBLK, 1024, 0, stream>>>(row, col, ea, blkh, btot, pea);
    k_p4<<<NB, 512, 0, stream>>>(pea, btot, x, offs, ea_sum, csr, emb0, W1, v3);
    // 2) hop 1: coalesced fp8-row gather (emb0, 1 node/wave) -> MFMA gemm -> emb8 (fp8)
    k_gather<<<(N_NODES * 64 + 255) / 256, 256, 0, stream>>>(emb0, offs, csr, aggB);
    k_gemm<false><<<(N_NODES + 63) / 64, 256, 0, stream>>>(
        aggB, w2p1, W1 + 1 * HID, v3 + 1 * HID, x, ea_sum, emb8, nullptr, nullptr, nullptr,
        nullptr, nullptr);
    // 3) hop 2: gather emb8 -> MFMA gemm + W7 head + fused pooling -> out partial, pooled
    k_gather<<<(N_NODES * 64 + 255) / 256, 256, 0, stream>>>(emb8, offs, csr, aggB);
    k_gemm<true><<<(N_NODES + 63) / 64, 256, 0, stream>>>(
        aggB, w2p2, W1 + 2 * HID, v3 + 2 * HID, x, ea_sum, nullptr, w7p, W5, out, bat, pooled);
    // 4) tail: per-graph scalar + bias add (fused)
    k_tail<<<(N_NODES + 255) / 256, 256, 0, stream>>>(out, bat, pooled, W6, W5, b5);
}

// Round 13
// 258.492 us; speedup vs baseline: 1.1335x; 1.0002x over previous
//
#include <hip/hip_runtime.h>
#include <hip/hip_bf16.h>

#define N_NODES 50000
#define N_EDGES 1600000
#define NGRAPH  16
#define HID     128

#define RPB   128                           // rows per bucket
#define NB    ((N_NODES + RPB - 1) / RPB)   // 391 buckets
#define NBLK  256                           // partition blocks
#define EPB   ((N_EDGES + NBLK - 1) / NBLK) // 6250 edges per partition block
#define P4CAP 6144                          // LDS cache entries for a bucket run (mean 4092, sd 64)

typedef unsigned int uint32;
typedef unsigned short ushort;
typedef unsigned char uchar;
typedef __attribute__((ext_vector_type(8))) short bf16x8;
typedef __attribute__((ext_vector_type(4))) float f32x4;
typedef __attribute__((ext_vector_type(2))) float f32x2;

// bf16 round-to-nearest-even helpers
__device__ __forceinline__ uint32 bf16r(float f) {
    uint32 b = __float_as_uint(f);
    return (b + 0x7fffu + ((b >> 16) & 1u)) >> 16;
}
__device__ __forceinline__ uint32 pack_bf16(float lo, float hi) {
    return bf16r(lo) | (bf16r(hi) << 16);
}

// ---------------- P1 + init (fused, r7-proven): per-(bucket,block) histogram;
//                  block-parallel weight prep (W2/W7 B-frag pack, v3), pooled zeroing ----
__global__ __launch_bounds__(1024) void k_p1i(const int* __restrict__ row,
                                              int* __restrict__ blkhist,
                                              float* __restrict__ zp, int nz,
                                              const float* __restrict__ W2,
                                              const float* __restrict__ W7,
                                              const float* __restrict__ W3,
                                              const float* __restrict__ W4,
                                              ushort* __restrict__ wpack,
                                              float* __restrict__ v3) {
    __shared__ int hist[NB];
    int tid = threadIdx.x, blk = blockIdx.x;
    int gid = blk * 1024 + tid;
    // --- init work (independent of hist) ---
    if (gid < nz) zp[gid] = 0.f;
    if (gid < 4 * 16384) {
        int m = gid >> 14, f = gid & 16383;
        int j = f & 7, lane = (f >> 3) & 63, kk = (f >> 9) & 3, t = (f >> 11) & 7;
        int hp = t * 16 + (lane & 15);
        int k  = kk * 32 + ((lane >> 4) & 3) * 8 + j;
        const float* src = (m < 3) ? (W2 + m * HID * HID) : W7;
        wpack[gid] = (ushort)bf16r(src[hp * HID + k]);
    }
    if (gid < 3 * HID) {
        int l = gid / HID, hp = gid % HID;
        float acc = 0.f;
        for (int h = 0; h < HID; h++)
            acc += W3[l * HID * HID + hp * HID + h] * fmaxf(W4[l * HID + h], 0.f);
        v3[gid] = acc;
    }
    // --- histogram ---
    for (int i = tid; i < NB; i += 1024) hist[i] = 0;
    __syncthreads();
    int s = blk * EPB, e = s + EPB; if (e > N_EDGES) e = N_EDGES;
    for (int i = s + tid; i < e; i += 1024)
        atomicAdd(&hist[row[i] >> 7], 1);
    __syncthreads();
    for (int i = tid; i < NB; i += 1024)
        blkhist[i * NBLK + blk] = hist[i];
}

// ------- P2a: per-bucket exclusive scan over its NBLK per-block counts -------
__global__ __launch_bounds__(NBLK) void k_p2a(int* __restrict__ blkhist,
                                              int* __restrict__ btot) {
    __shared__ int sums[NBLK];
    int t = threadIdx.x, b = blockIdx.x;
    int v = blkhist[b * NBLK + t];
    sums[t] = v;
    __syncthreads();
    for (int d = 1; d < NBLK; d <<= 1) {
        int u = (t >= d) ? sums[t - d] : 0;
        __syncthreads();
        sums[t] += u;
        __syncthreads();
    }
    blkhist[b * NBLK + t] = sums[t] - v;     // local exclusive
    if (t == NBLK - 1) btot[b] = sums[t];    // bucket total
}

// ------- P3: scatter int2{rowlocal:8|col:16, ea} into bucket runs -------
// (bucket bases recomputed per-block from btot via LDS scan)
__global__ __launch_bounds__(1024) void k_p3_part(const int* __restrict__ row,
                                                  const int* __restrict__ col,
                                                  const float* __restrict__ ea,
                                                  const int* __restrict__ blkhist,
                                                  const int* __restrict__ btot,
                                                  int2* __restrict__ pea) {
    __shared__ int sc[512];
    __shared__ int cur[NB];
    int tid = threadIdx.x, blk = blockIdx.x;
    if (tid < 512) sc[tid] = (tid < NB) ? btot[tid] : 0;
    __syncthreads();
    for (int d = 1; d < 512; d <<= 1) {
        int v = 0;
        if (tid < 512 && tid >= d) v = sc[tid - d];
        __syncthreads();
        if (tid < 512) sc[tid] += v;
        __syncthreads();
    }
    for (int i = tid; i < NB; i += 1024)
        cur[i] = (sc[i] - btot[i]) + blkhist[i * NBLK + blk];
    __syncthreads();
    int s = blk * EPB, e = s + EPB; if (e > N_EDGES) e = N_EDGES;
    for (int i = s + tid; i < e; i += 1024) {
        int r = row[i], c = col[i];
        float a = ea[i];
        int slot = atomicAdd(&cur[r >> 7], 1);
        pea[slot] = make_int2(((r & (RPB - 1)) << 16) | c, __float_as_int(a));
    }
}

// ------- P4: bucket run staged in LDS once; counts+scan -> offs/ea_sum, scatter csr,
//         and materialize emb0[n] = relu(x[n]*w1 + ea_sum[n]*v3) as fp8 rows (scale 2^-6). -------
__global__ __launch_bounds__(512) void k_p4(const int2* __restrict__ pea,
                                            const int* __restrict__ btot,
                                            const float* __restrict__ x,
                                            int* __restrict__ offs,
                                            float* __restrict__ ea_sum,
                                            int* __restrict__ csr,
                                            uchar* __restrict__ emb0,
                                            const float* __restrict__ w1l0,
                                            const float* __restrict__ v3l0) {
    __shared__ int2  cache[P4CAP];   // 48 KB
    __shared__ int   red[512];
    __shared__ int   cnt[RPB];
    __shared__ float eas[RPB];
    __shared__ int   scan_s[RPB];
    __shared__ int   curp[RPB];
    int t = threadIdx.x, b = blockIdx.x;
    // bucket base s = sum(btot[0..b)), e = s + btot[b]
    red[t] = (t < b) ? btot[t] : 0;          // t<b implies t<NB
    __syncthreads();
    for (int d = 256; d > 0; d >>= 1) {
        if (t < d) red[t] += red[t + d];
        __syncthreads();
    }
    int s = red[0];
    int e = s + btot[b];
    int len = e - s;
    int clen = len < P4CAP ? len : P4CAP;    // statistical bound: len never exceeds P4CAP
    for (int i = t; i < clen; i += 512) cache[i] = pea[s + i];
    if (t < RPB) { cnt[t] = 0; eas[t] = 0.f; }
    __syncthreads();
    // pass 1: per-node counts + ea sums
    for (int i = t; i < len; i += 512) {
        int2 p = (i < P4CAP) ? cache[i] : pea[s + i];
        int lr = ((uint32)p.x) >> 16;
        atomicAdd(&cnt[lr], 1);
        atomicAdd(&eas[lr], __int_as_float(p.y));
    }
    __syncthreads();
    if (t < RPB) scan_s[t] = cnt[t];
    __syncthreads();
    for (int d = 1; d < RPB; d <<= 1) {
        int v = 0;
        if (t < RPB && t >= d) v = scan_s[t - d];
        __syncthreads();
        if (t < RPB) scan_s[t] += v;
        __syncthreads();
    }
    int nbase = b * RPB;
    if (t < RPB) {
        int excl = scan_s[t] - cnt[t];
        int n = nbase + t;
        if (n < N_NODES) {
            offs[n] = s + excl;
            ea_sum[n] = eas[t];
        }
        curp[t] = s + excl;
    }
    if (b == NB - 1 && t == 0) offs[N_NODES] = e;
    __syncthreads();
    // pass 2: scatter csr from the LDS-cached run
    for (int i = t; i < len; i += 512) {
        int2 p = (i < P4CAP) ? cache[i] : pea[s + i];
        int slot = atomicAdd(&curp[((uint32)p.x) >> 16], 1);
        csr[slot] = p.x & 0xFFFF;
    }
    // epilogue: emb0 fp8 rows for this bucket's 128 nodes (coalesced 16 KB write)
    for (int i = t; i < RPB * 32; i += 512) {
        int lr = i >> 5, c4 = (i & 31) * 4;
        int n = nbase + lr;
        if (n < N_NODES) {
            float xv = x[n];
            float ev = eas[lr];
            float v0 = fmaxf(xv * w1l0[c4 + 0] + ev * v3l0[c4 + 0], 0.f) * 0.015625f;
            float v1 = fmaxf(xv * w1l0[c4 + 1] + ev * v3l0[c4 + 1], 0.f) * 0.015625f;
            float v2 = fmaxf(xv * w1l0[c4 + 2] + ev * v3l0[c4 + 2], 0.f) * 0.015625f;
            float v3v = fmaxf(xv * w1l0[c4 + 3] + ev * v3l0[c4 + 3], 0.f) * 0.015625f;
            int u = __builtin_amdgcn_cvt_pk_fp8_f32(v0, v1, 0, false);
            u = __builtin_amdgcn_cvt_pk_fp8_f32(v2, v3v, u, true);
            *(uint32*)(emb0 + (size_t)n * 128 + c4) = (uint32)u;
        }
    }
}

// ------- gather over fp8 emb rows (128 B): 1 node/wave, 2 B/lane (best-verified shape) -------
// readlane (compile-time lane idx) -> scalar neighbor index -> SGPR-based row address;
// 16-deep load pipeline for L2 latency hiding. Used for BOTH hops.
__global__ __launch_bounds__(256) void k_gather(const uchar* __restrict__ emb,
                                                const int* __restrict__ offs,
                                                const int* __restrict__ csr,
                                                uint32* __restrict__ agg) {
    int node = (blockIdx.x * 256 + threadIdx.x) >> 6;
    int lane = threadIdx.x & 63;
    if (node >= N_NODES) return;
    int s = offs[node], e = offs[node + 1];
    int off2 = 2 * lane;
    float ax[8] = {0.f}, ay[8] = {0.f};
    for (int base = s; base < e; base += 64) {
        int idx = base + lane;
        int cv = (idx < e) ? csr[idx] : 0;     // one coalesced load per 64 edges
        int cnt = e - base; if (cnt > 64) cnt = 64;
        int j = 0;
        for (; j + 16 <= cnt; j += 16) {
            int h16[16];
#pragma unroll
            for (int u = 0; u < 16; u++) {
                uint32 c = (uint32)__builtin_amdgcn_readlane(cv, j + u);  // SGPR index
                h16[u] = *(const ushort*)(emb + (((size_t)c) << 7) + off2);
            }
#pragma unroll
            for (int u = 0; u < 16; u++) {
                f32x2 d = __builtin_amdgcn_cvt_pk_f32_fp8(h16[u], false);
                ax[u & 7] += d.x; ay[u & 7] += d.y;
            }
        }
        for (; j + 4 <= cnt; j += 4) {
            int h4[4];
#pragma unroll
            for (int u = 0; u < 4; u++) {
                uint32 c = (uint32)__builtin_amdgcn_readlane(cv, j + u);
                h4[u] = *(const ushort*)(emb + (((size_t)c) << 7) + off2);
            }
#pragma unroll
            for (int u = 0; u < 4; u++) {
                f32x2 d = __builtin_amdgcn_cvt_pk_f32_fp8(h4[u], false);
                ax[u] += d.x; ay[u] += d.y;
            }
        }
        for (; j < cnt; j++) {
            uint32 c = (uint32)__builtin_amdgcn_readlane(cv, j);
            int h = *(const ushort*)(emb + (((size_t)c) << 7) + off2);
            f32x2 d = __builtin_amdgcn_cvt_pk_f32_fp8(h, false);
            ax[0] += d.x; ay[0] += d.y;
        }
    }
    float rx = (((ax[0] + ax[1]) + (ax[2] + ax[3])) + ((ax[4] + ax[5]) + (ax[6] + ax[7]))) * 64.f;
    float ry = (((ay[0] + ay[1]) + (ay[2] + ay[3])) + ((ay[4] + ay[5]) + (ay[6] + ay[7]))) * 64.f;
    agg[(size_t)node * 64 + lane] = pack_bf16(rx, ry);
}

#define LROW 136  // padded LDS row, bf16 elems

// ------- MFMA GEMM hop: emb = relu(agg @ W2T + x*w1 + ea*v3) -------
// A-fragments load directly from global (aggB word layout == fragment order).
// !LAST: fp8 emb out (scale 2^-6).  LAST: fused W7 head + graph pooling.
template <bool LAST>
__global__ __launch_bounds__(256) void k_gemm(const uint32* __restrict__ agg,   // bf16 [N][64u32]
                                              const ushort* __restrict__ w2p,   // B-frag packed
                                              const float* __restrict__ w1l,
                                              const float* __restrict__ v3l,
                                              const float* __restrict__ x,
                                              const float* __restrict__ ea_sum,
                                              uchar* __restrict__ emb8Out,      // fp8 (!LAST)
                                              const ushort* __restrict__ w7p,
                                              const float* __restrict__ W5,
                                              float* __restrict__ outp,
                                              const int* __restrict__ batch,
                                              float* __restrict__ pooled) {
    __shared__ ushort tile[64 * LROW]; // 17408 B (epilogue staging only)
    __shared__ float redp[4][128];     // pooling cross-wave reduce (LAST)
    int tid = threadIdx.x;
    int tbase = blockIdx.x * 64;
    int wv = tid >> 6, lane = tid & 63;
    int n0 = lane & 15, quad = lane >> 4;
    int arow = wv * 16 + n0;
    bf16x8 a0 = {0,0,0,0,0,0,0,0}, a1 = a0, a2 = a0, a3 = a0;
    if (tbase + arow < N_NODES) {
        const bf16x8* ap = (const bf16x8*)(agg + (size_t)(tbase + arow) * 64);
        a0 = ap[0 + quad]; a1 = ap[4 + quad]; a2 = ap[8 + quad]; a3 = ap[12 + quad];
    }
    const bf16x8* wb = (const bf16x8*)w2p;
    f32x4 acc[8];
#pragma unroll
    for (int t = 0; t < 8; t++) {
        f32x4 c = {0.f, 0.f, 0.f, 0.f};
        c = __builtin_amdgcn_mfma_f32_16x16x32_bf16(a0, wb[(t * 4 + 0) * 64 + lane], c, 0, 0, 0);
        c = __builtin_amdgcn_mfma_f32_16x16x32_bf16(a1, wb[(t * 4 + 1) * 64 + lane], c, 0, 0, 0);
        c = __builtin_amdgcn_mfma_f32_16x16x32_bf16(a2, wb[(t * 4 + 2) * 64 + lane], c, 0, 0, 0);
        c = __builtin_amdgcn_mfma_f32_16x16x32_bf16(a3, wb[(t * 4 + 3) * 64 + lane], c, 0, 0, 0);
        acc[t] = c;
    }
    float xs[4], es[4];
#pragma unroll
    for (int r = 0; r < 4; r++) {
        int n = tbase + wv * 16 + quad * 4 + r;
        xs[r] = (n < N_NODES) ? x[n] : 0.f;
        es[r] = (n < N_NODES) ? ea_sum[n] : 0.f;
    }
    if (!LAST) {
        // epilogue: fp8 output, scale 2^-6 (exact pow2; rescaled x64 in k_gather)
        uchar* stile = (uchar*)tile;   // rows stride 136 B; wave-private rows
#pragma unroll
        for (int t = 0; t < 8; t++) {
            int hp = t * 16 + n0;
            float w1v = w1l[hp], v3v = v3l[hp];
#pragma unroll
            for (int r = 0; r < 4; r++) {
                float v = fmaxf(acc[t][r] + xs[r] * w1v + es[r] * v3v, 0.f) * 0.015625f;
                int enc = __builtin_amdgcn_cvt_pk_fp8_f32(v, v, 0, false);
                stile[(wv * 16 + quad * 4 + r) * 136 + hp] = (uchar)(enc & 0xff);
            }
        }
        __syncthreads();
        int vn = N_NODES - tbase; if (vn > 64) vn = 64;
        for (int i = tid; i < 64 * 32; i += 256) {
            int r = i >> 5, c4 = (i & 31) * 4;
            if (r < vn) {
                uint32 u = *(const uint32*)&stile[r * 136 + c4];
                *(uint32*)(emb8Out + (size_t)(tbase + r) * 128 + c4) = u;
            }
        }
    } else {
        // epilogue: bf16 through LDS for W7 head; fused graph pooling
        int nlast = tbase + 63; if (nlast > N_NODES - 1) nlast = N_NODES - 1;
        int g0 = batch[tbase];
        bool uni = (batch[nlast] == g0);           // block-uniform
        int gr[4];
        if (!uni) {
#pragma unroll
            for (int r = 0; r < 4; r++) {
                int n = tbase + wv * 16 + quad * 4 + r;
                gr[r] = (n < N_NODES) ? batch[n] : 0;
            }
        }
        float st[8];
#pragma unroll
        for (int t = 0; t < 8; t++) {
            int hp = t * 16 + n0;
            float w1v = w1l[hp], v3v = v3l[hp];
            float stt = 0.f;
#pragma unroll
            for (int r = 0; r < 4; r++) {
                float v = fmaxf(acc[t][r] + xs[r] * w1v + es[r] * v3v, 0.f);
                tile[(wv * 16 + quad * 4 + r) * LROW + hp] = (ushort)bf16r(v);
                if (uni) {
                    stt += v;   // invalid rows contribute exactly 0 (zeroed frags + xs/es)
                } else {
                    int n = tbase + wv * 16 + quad * 4 + r;
                    if (n < N_NODES) atomicAdd(&pooled[gr[r] * HID + hp], v);
                }
            }
            st[t] = stt;
        }
        if (uni) {
#pragma unroll
            for (int t = 0; t < 8; t++) {
                float v = st[t];
                v += __shfl_xor(v, 16);
                v += __shfl_xor(v, 32);
                if (lane < 16) redp[wv][t * 16 + lane] = v;
            }
        }
        __syncthreads();
        if (uni && tid < 128) {
            float sp = (redp[0][tid] + redp[1][tid]) + (redp[2][tid] + redp[3][tid]);
            atomicAdd(&pooled[g0 * HID + tid], sp);
        }
        bf16x8 b0 = *(const bf16x8*)&tile[arow * LROW + 0 * 32 + quad * 8];
        bf16x8 b1 = *(const bf16x8*)&tile[arow * LROW + 1 * 32 + quad * 8];
        bf16x8 b2 = *(const bf16x8*)&tile[arow * LROW + 2 * 32 + quad * 8];
        bf16x8 b3 = *(const bf16x8*)&tile[arow * LROW + 3 * 32 + quad * 8];
        const bf16x8* w7 = (const bf16x8*)w7p;
        float p[4] = {0.f, 0.f, 0.f, 0.f};
#pragma unroll
        for (int t = 0; t < 8; t++) {
            f32x4 c = {0.f, 0.f, 0.f, 0.f};
            c = __builtin_amdgcn_mfma_f32_16x16x32_bf16(b0, w7[(t * 4 + 0) * 64 + lane], c, 0, 0, 0);
            c = __builtin_amdgcn_mfma_f32_16x16x32_bf16(b1, w7[(t * 4 + 1) * 64 + lane], c, 0, 0, 0);
            c = __builtin_amdgcn_mfma_f32_16x16x32_bf16(b2, w7[(t * 4 + 2) * 64 + lane], c, 0, 0, 0);
            c = __builtin_amdgcn_mfma_f32_16x16x32_bf16(b3, w7[(t * 4 + 3) * 64 + lane], c, 0, 0, 0);
            float w5v = W5[128 + t * 16 + n0];
#pragma unroll
            for (int r = 0; r < 4; r++) p[r] += fmaxf(c[r], 0.f) * w5v;
        }
#pragma unroll
        for (int r = 0; r < 4; r++) {
            float v = p[r];
            v += __shfl_xor(v, 1);
            v += __shfl_xor(v, 2);
            v += __shfl_xor(v, 4);
            v += __shfl_xor(v, 8);
            int n = tbase + wv * 16 + quad * 4 + r;
            if (n0 == 0 && n < N_NODES) outp[n] = v;
        }
    }
}

// ------- tail (fused k_graph + k_addsg): per-block compute the <=2 needed s_g, add -------
__global__ __launch_bounds__(256) void k_tail(float* __restrict__ out,
                                              const int* __restrict__ batch,
                                              const float* __restrict__ pooled,
                                              const float* __restrict__ W6,
                                              const float* __restrict__ W5,
                                              const float* __restrict__ b5) {
    __shared__ float red[256];
    __shared__ int gsh[2];
    int t = threadIdx.x;
    int nbase = blockIdx.x * 256;
    int n = nbase + t;
    if (t == 0) gsh[0] = batch[nbase < N_NODES ? nbase : N_NODES - 1];
    if (t == 1) gsh[1] = batch[(nbase + 255) < N_NODES ? (nbase + 255) : N_NODES - 1];
    __syncthreads();
    int g_lo = gsh[0], g_hi = gsh[1];
    int hp = t & 127;
    int g = (t >> 7) ? g_hi : g_lo;
    const float* pg = pooled + g * HID;
    const float* wr = W6 + hp * HID;
    float acc = 0.f;
    for (int h = 0; h < HID; h++) acc += pg[h] * wr[h];
    red[t] = fmaxf(acc, 0.f) * W5[hp];
    __syncthreads();
    for (int d = 64; d > 0; d >>= 1) {
        if (hp < d) red[t] += red[t + d];
        __syncthreads();
    }
    float s_lo = red[0], s_hi = red[128];
    if (n < N_NODES) {
        int gn = batch[n];
        float s;
        if (gn == g_lo) s = s_lo;
        else if (gn == g_hi) s = s_hi;
        else {   // middle graph inside one 256-block: impossible for this input, kept for safety
            s = 0.f;
            const float* pg2 = pooled + gn * HID;
            for (int hp2 = 0; hp2 < HID; hp2++) {
                float a2 = 0.f;
                for (int h = 0; h < HID; h++) a2 += pg2[h] * W6[hp2 * HID + h];
                s += fmaxf(a2, 0.f) * W5[hp2];
            }
        }
        out[n] += s + b5[0];
    }
}

extern "C" void kernel_launch(void* const* d_in, const int* in_sizes, int n_in,
                              void* d_out, int out_size, void* d_ws, size_t ws_size,
                              hipStream_t stream) {
    (void)in_sizes; (void)n_in; (void)out_size; (void)ws_size;
    const float* x    = (const float*)d_in[0];
    const int*   ei   = (const int*)d_in[1];   // [2,E] flat: row then col
    const float* ea   = (const float*)d_in[2];
    const int*   bat  = (const int*)d_in[3];
    const float* W1   = (const float*)d_in[4]; // [3,128,1]
    const float* W2   = (const float*)d_in[5]; // [3,128,128]
    const float* W3   = (const float*)d_in[6];
    const float* W4   = (const float*)d_in[7]; // [3,128,1]
    const float* W5   = (const float*)d_in[8]; // [1,256]
    const float* b5   = (const float*)d_in[9];
    const float* W6   = (const float*)d_in[10];
    const float* W7   = (const float*)d_in[11];
    float* out = (float*)d_out;

    const int* row = ei;
    const int* col = ei + N_EDGES;

    // workspace layout (4B elems)
    float* wsf = (float*)d_ws;
    int*   wsi = (int*)d_ws;
    size_t o = 0;
    float* pooled = wsf + o; o += NGRAPH * HID;     // zeroed (atomic target)
    size_t ztot = o;                                // 2048
    int*   offs   = wsi + o; o += N_NODES + 1;
    float* ea_sum = wsf + o; o += N_NODES;
    int*   btot   = wsi + o; o += NB;
    float* v3     = wsf + o; o += 3 * HID;
    int*   blkh   = wsi + o; o += NB * NBLK;
    o = (o + 3) & ~(size_t)3;
    ushort* wpack = (ushort*)(wsi + o); o += 4 * 16384 / 2;
    int*    csr   = wsi + o; o += N_EDGES;
    o = (o + 1) & ~(size_t)1;
    int2*   pea   = (int2*)(wsi + o); o += 2 * (size_t)N_EDGES;
    uint32* aggB  = (uint32*)(wsi + o); o += (size_t)N_NODES * 64;  // bf16 [N][128], frag order
    uchar*  emb8  = (uchar*)(wsi + o);  o += (size_t)N_NODES * 32;  // fp8  [N][128] hop-2 emb
    uchar*  emb0  = (uchar*)(wsi + o);  o += (size_t)N_NODES * 32;  // fp8  [N][128] hop-1 emb

    const ushort* w2p1 = wpack + 1 * 16384;
    const ushort* w2p2 = wpack + 2 * 16384;
    const ushort* w7p  = wpack + 3 * 16384;

    // 1) histogram + fused init (zero pooled, weight prep, v3) — r7-proven fusion
    k_p1i<<<NBLK, 1024, 0, stream>>>(row, blkh, (float*)d_ws, (int)ztot,
                                     W2, W7, W3, W4, (ushort*)wpack, v3);
    // 2) CSR build; p4 also materializes emb0 (fp8 layer-0 embeddings)
    k_p2a<<<NB, NBLK, 0, stream>>>(blkh, btot);
    k_p3_part<<<NBLK, 1024, 0, stream>>>(row, col, ea, blkh, btot, pea);
    k_p4<<<NB, 512, 0, stream>>>(pea, btot, x, offs, ea_sum, csr, emb0, W1, v3);
    // 3) hop 1: coalesced fp8-row gather (emb0, 1 node/wave) -> MFMA gemm -> emb8 (fp8)
    k_gather<<<(N_NODES * 64 + 255) / 256, 256, 0, stream>>>(emb0, offs, csr, aggB);
    k_gemm<false><<<(N_NODES + 63) / 64, 256, 0, stream>>>(
        aggB, w2p1, W1 + 1 * HID, v3 + 1 * HID, x, ea_sum, emb8, nullptr, nullptr, nullptr,
        nullptr, nullptr);
    // 4) hop 2: gather emb8 -> MFMA gemm + W7 head + fused pooling -> out partial, pooled
    k_gather<<<(N_NODES * 64 + 255) / 256, 256, 0, stream>>>(emb8, offs, csr, aggB);
    k_gemm<true><<<(N_NODES + 63) / 64, 256, 0, stream>>>(
        aggB, w2p2, W1 + 2 * HID, v3 + 2 * HID, x, ea_sum, nullptr, w7p, W5, out, bat, pooled);
    // 5) tail: per-graph scalar + bias add (fused)
    k_tail<<<(N_NODES + 255) / 256, 256, 0, stream>>>(out, bat, pooled, W6, W5, b5);
}